// Round 7
// baseline (420.426 us; speedup 1.0000x reference)
//
#include <hip/hip_runtime.h>
#include <stdint.h>
#include <math.h>

#define NUM_TOK 8192
#define DM 512
#define NE 8
#define NH 2048
#define MAX_TILES 72   // ceil-sum of per-expert 128-row tiles <= 64 + 7

typedef float f32x4 __attribute__((ext_vector_type(4)));
typedef __bf16 bf16x8 __attribute__((ext_vector_type(8)));

// ws layout (bytes)
#define WS_COUNTS   0                 // int[8]
#define WS_CURSORS  32                // int[8]
#define WS_OFFSETS  64                // int[8]
#define WS_IMP      96                // (unused)
#define WS_TILE_E   128               // int[72]
#define WS_TILE_R0  416               // int[72]
#define WS_EXP      704               // int[8192]
#define WS_WTOK     33472             // float[8192]
#define WS_PERM     66240             // int[8192]; first 256 B double as imp shards (read before scatter)
#define WS_XG       99008             // bf16 (8192+128) x 512
#define WS_H        8618688           // bf16 (8192+128) x 2048
#define WS_W1T      42697408          // bf16 [8][2048][512]  = 16 MB
#define WS_W2T      59474624          // bf16 [8][512][2048]  = 16 MB

__device__ __forceinline__ uint16_t f2bf(float f) {
  union { float f; uint32_t u; } c; c.f = f;
  return (uint16_t)((c.u + 0x7FFFu + ((c.u >> 16) & 1u)) >> 16);
}

__device__ __forceinline__ float gelu_fast(float v) {
  float z = 1.5957691216f * v * (1.0f + 0.044715f * v * v);
  float em = __expf(-z);
  return v / (1.0f + em);
}

__device__ __forceinline__ void gload_lds16(const void* g, void* l) {
  __builtin_amdgcn_global_load_lds(
      (const __attribute__((address_space(1))) uint32_t*)g,
      (__attribute__((address_space(3))) uint32_t*)l, 16, 0, 0);
}

// raw barrier primitives: keep DMA prefetch in flight across the barrier
#define WAIT_BARRIER(N) asm volatile("s_waitcnt vmcnt(" #N ")\ns_barrier" ::: "memory")
#define RAW_BARRIER()   asm volatile("s_barrier" ::: "memory")

// ---------------- router: one wave per token ----------------
// lanes split K (8 d's each, fp64), shuffle all-reduce, transcendentals on lanes 0-7
__global__ __launch_bounds__(256) void k_router(
    const float* __restrict__ x, const float* __restrict__ u,
    const float* __restrict__ rw, const float* __restrict__ rb,
    int* __restrict__ counts, float* __restrict__ imp_sh,
    int* __restrict__ expert_of, float* __restrict__ wtok)
{
  int wv = threadIdx.x >> 6, lane = threadIdx.x & 63;
  int t = blockIdx.x * 4 + wv;

  const float4* xr = (const float4*)(x + (size_t)t * DM + lane * 8);
  float4 xa = xr[0], xb = xr[1];
  float xs[8] = {xa.x, xa.y, xa.z, xa.w, xb.x, xb.y, xb.z, xb.w};

  double acc[NE];
  #pragma unroll
  for (int e = 0; e < NE; ++e) acc[e] = 0.0;
  #pragma unroll
  for (int j = 0; j < 8; ++j) {
    const float4* rr = (const float4*)(rw + (size_t)(lane * 8 + j) * NE);
    float4 r0 = rr[0], r1 = rr[1];
    double xv = (double)xs[j];
    acc[0] += xv * (double)r0.x; acc[1] += xv * (double)r0.y;
    acc[2] += xv * (double)r0.z; acc[3] += xv * (double)r0.w;
    acc[4] += xv * (double)r1.x; acc[5] += xv * (double)r1.y;
    acc[6] += xv * (double)r1.z; acc[7] += xv * (double)r1.w;
  }
  // all-reduce over 64 lanes (fp64 tree; reassociation harmless at fp64)
  #pragma unroll
  for (int m = 1; m < 64; m <<= 1) {
    #pragma unroll
    for (int e = 0; e < NE; ++e) acc[e] += __shfl_xor(acc[e], m, 64);
  }
  double lg[NE];
  #pragma unroll
  for (int e = 0; e < NE; ++e) lg[e] = acc[e] + (double)rb[e];

  int le = lane & 7;
  double lgE = le == 0 ? lg[0] : le == 1 ? lg[1] : le == 2 ? lg[2] : le == 3 ? lg[3]
             : le == 4 ? lg[4] : le == 5 ? lg[5] : le == 6 ? lg[6] : lg[7];

  // gumbel on lanes 0-7 (one expert each)
  double yE = -1e300;
  if (lane < 8) {
    double uv = (double)u[(size_t)t * NE + lane];
    double g = -log(-log(uv) + 1e-10);
    yE = lgE + g;
  }
  double ymax = yE;
  #pragma unroll
  for (int m = 1; m < 8; m <<= 1) ymax = fmax(ymax, __shfl_xor(ymax, m, 64));
  double ex = (lane < 8) ? exp(yE - ymax) : 0.0;
  double s = ex;
  #pragma unroll
  for (int m = 1; m < 8; m <<= 1) s += __shfl_xor(s, m, 64);
  double p = 1.0 / s;                       // y_soft at selected (y_sel == ymax)
  unsigned long long mk = __ballot(lane < 8 && yE == ymax);
  int sel = __ffsll(mk) - 1;                // first max wins

  // importance: softmax(logits), distributed over lanes 0-7
  double lm = lgE;
  #pragma unroll
  for (int m = 1; m < 8; m <<= 1) lm = fmax(lm, __shfl_xor(lm, m, 64));
  double pr = exp(lgE - lm);
  double ssum = pr;
  #pragma unroll
  for (int m = 1; m < 8; m <<= 1) ssum += __shfl_xor(ssum, m, 64);
  float v = (float)(pr / ssum);
  if (lane < 8) atomicAdd(&imp_sh[(blockIdx.x & 7) * 8 + lane], v);
  if (lane == 0) {
    expert_of[t] = sel;
    wtok[t] = (float)((1.0 - p) + p);
    atomicAdd(&counts[sel], 1);
  }
}

// ---------------- offsets + aux loss + compact tile table ----------------
__global__ void k_aux_offsets(const int* __restrict__ counts, const float* __restrict__ imp_sh,
                              int* __restrict__ offsets, float* __restrict__ aux_out,
                              int* __restrict__ tile_e, int* __restrict__ tile_r0)
{
  if (threadIdx.x == 0) {
    int o = 0;
    for (int e = 0; e < NE; ++e) { offsets[e] = o; o += counts[e]; }
    float a = 0.0f;
    for (int e = 0; e < NE; ++e) {
      float im = 0.0f;
      for (int sh = 0; sh < 8; ++sh) im += imp_sh[sh * 8 + e];
      float dv = im / 8192.0f - 0.125f;
      a += dv * dv;
    }
    aux_out[0] = a / 8.0f;
    int nt = 0;
    for (int e = 0; e < NE; ++e) {
      int ntile = (counts[e] + 127) >> 7;
      for (int j = 0; j < ntile; ++j) {
        tile_e[nt] = e;
        tile_r0[nt] = offsets[e] + j * 128;
        ++nt;
      }
    }
    for (int i = nt; i < MAX_TILES; ++i) { tile_e[i] = -1; tile_r0[i] = 0; }
  }
}

// ---------------- counting-sort scatter: perm[pos] = token ----------------
__global__ __launch_bounds__(256) void k_scatter(
    const int* __restrict__ expert_of, const int* __restrict__ offsets,
    int* __restrict__ cursors, int* __restrict__ perm)
{
  int t = blockIdx.x * 256 + threadIdx.x;
  int e = expert_of[t];
  int pos = offsets[e] + atomicAdd(&cursors[e], 1);
  perm[pos] = t;
}

// ---------------- gather x rows into sorted bf16 Xg ----------------
__global__ __launch_bounds__(64) void k_gather(
    const float* __restrict__ x, const int* __restrict__ perm, uint16_t* __restrict__ Xg)
{
  int r = blockIdx.x;
  int lane = threadIdx.x;
  int t = perm[r];
  const float4* src = (const float4*)(x + (size_t)t * DM);
  float4 a = src[lane * 2];
  float4 b = src[lane * 2 + 1];
  uint32_t p0 = (uint32_t)f2bf(a.x) | ((uint32_t)f2bf(a.y) << 16);
  uint32_t p1 = (uint32_t)f2bf(a.z) | ((uint32_t)f2bf(a.w) << 16);
  uint32_t p2 = (uint32_t)f2bf(b.x) | ((uint32_t)f2bf(b.y) << 16);
  uint32_t p3 = (uint32_t)f2bf(b.z) | ((uint32_t)f2bf(b.w) << 16);
  uint4 v = make_uint4(p0, p1, p2, p3);
  ((uint4*)(Xg + (size_t)r * DM))[lane] = v;
}

// ---------------- weight transpose+convert: src [e][K][N] f32 -> dst [e][N][K] bf16 ----------------
__global__ __launch_bounds__(256) void k_transpose_bf16(
    const float* __restrict__ src, uint16_t* __restrict__ dst, int K, int N)
{
  __shared__ float T[64][65];
  int e = blockIdx.z;
  const float* s = src + (size_t)e * K * N;
  uint16_t* d = dst + (size_t)e * K * N;
  int n0 = blockIdx.x * 64, k0 = blockIdx.y * 64;
  int tid = threadIdx.x;
  int tr = tid >> 4;
  int tc = (tid & 15) * 4;
  #pragma unroll
  for (int p = 0; p < 4; ++p) {
    int k = tr + p * 16;
    float4 v = *(const float4*)(s + (size_t)(k0 + k) * N + n0 + tc);
    T[k][tc] = v.x; T[k][tc + 1] = v.y; T[k][tc + 2] = v.z; T[k][tc + 3] = v.w;
  }
  __syncthreads();
  #pragma unroll
  for (int p = 0; p < 2; ++p) {
    int slot = p * 256 + tid;
    int n = slot >> 3;
    int c = (slot & 7) * 8;
    uint16_t tmp[8];
    #pragma unroll
    for (int j = 0; j < 8; ++j) tmp[j] = f2bf(T[c + j][n]);
    *(uint4*)(d + (size_t)(n0 + n) * K + k0 + c) = *(uint4*)tmp;
  }
}

// shared MFMA tile compute (rows = 128, cols = NCOLS*32 via wn span)
__device__ __forceinline__ void mfma_128x128(
    const uint16_t* Asb, const uint16_t* Bsb, f32x4 (&acc)[4][4],
    int wm, int wn, int l16, int quad)
{
  #pragma unroll
  for (int ks = 0; ks < 2; ++ks) {
    bf16x8 a[4], b[4];
    #pragma unroll
    for (int mi = 0; mi < 4; ++mi) {
      int row = wm * 64 + mi * 16 + l16;
      a[mi] = *(const bf16x8*)(Asb + row * 64 + (((ks * 4 + quad) ^ (l16 & 7)) * 8));
    }
    #pragma unroll
    for (int ni = 0; ni < 4; ++ni) {
      int row = wn * 64 + ni * 16 + l16;
      b[ni] = *(const bf16x8*)(Bsb + row * 64 + (((ks * 4 + quad) ^ (l16 & 7)) * 8));
    }
    #pragma unroll
    for (int mi = 0; mi < 4; ++mi)
      #pragma unroll
      for (int ni = 0; ni < 4; ++ni)
        acc[mi][ni] = __builtin_amdgcn_mfma_f32_16x16x32_bf16(a[mi], b[ni], acc[mi][ni], 0, 0, 0);
  }
}

// ---------------- layer 1: h = gelu(Xg @ w1t[e]^T + b1[e]) ----------------
// grid (MAX_TILES, 16). Double-buffered async DMA staging, 2-iter prefetch,
// raw s_barrier + fine-grained vmcnt (prefetch survives the barrier).
__global__ __launch_bounds__(256) void k_ffn1(
    const uint16_t* __restrict__ Xg, const uint16_t* __restrict__ w1t,
    const float* __restrict__ b1,
    const int* __restrict__ offsets, const int* __restrict__ counts,
    const int* __restrict__ tile_e, const int* __restrict__ tile_r0,
    uint16_t* __restrict__ hbuf)
{
  int e = tile_e[blockIdx.x];
  if (e < 0) return;
  int row0 = tile_r0[blockIdx.x];
  int row_end = offsets[e] + counts[e];
  int n0 = blockIdx.y * 128;
  const uint16_t* Bt = w1t + (size_t)e * DM * NH;

  __shared__ uint16_t As[2][128 * 64];
  __shared__ uint16_t Bs[2][128 * 64];

  int tid = threadIdx.x;
  int lane = tid & 63, wid = tid >> 6;
  int wm = wid >> 1, wn = wid & 1;
  int l16 = lane & 15, quad = lane >> 4;

  int lrow = lane >> 3;
  int lsw  = (lane & 7) ^ lrow;
  const uint16_t *ga[4], *gb[4];
  int lo[4];
  #pragma unroll
  for (int j = 0; j < 4; ++j) {
    int r = wid * 32 + j * 8;
    ga[j] = Xg + (size_t)(row0 + r + lrow) * DM + lsw * 8;
    gb[j] = Bt + (size_t)(n0 + r + lrow) * DM + lsw * 8;
    lo[j] = r * 64;
  }

  #define FFN1_ISSUE(B) do { \
    _Pragma("unroll") for (int j = 0; j < 4; ++j) { gload_lds16(ga[j], As[B] + lo[j]); ga[j] += 64; } \
    _Pragma("unroll") for (int j = 0; j < 4; ++j) { gload_lds16(gb[j], Bs[B] + lo[j]); gb[j] += 64; } \
  } while (0)

  f32x4 acc[4][4] = {};

  FFN1_ISSUE(0);
  FFN1_ISSUE(1);
  #pragma unroll 2
  for (int k = 0; k < 8; ++k) {
    if (k < 7) WAIT_BARRIER(8); else WAIT_BARRIER(0);
    int b = k & 1;
    mfma_128x128(As[b], Bs[b], acc, wm, wn, l16, quad);
    RAW_BARRIER();
    if (k < 6) { if (b) FFN1_ISSUE(1); else FFN1_ISSUE(0); }
  }

  #pragma unroll
  for (int ni = 0; ni < 4; ++ni) {
    int col = n0 + wn * 64 + ni * 16 + l16;
    float bv = b1[e * NH + col];
    #pragma unroll
    for (int mi = 0; mi < 4; ++mi) {
      int rbase = wm * 64 + mi * 16 + quad * 4;
      #pragma unroll
      for (int r = 0; r < 4; ++r) {
        int grow = row0 + rbase + r;
        if (grow < row_end) {
          float v = acc[mi][ni][r] + bv;
          hbuf[(size_t)grow * NH + col] = f2bf(gelu_fast(v));
        }
      }
    }
  }
}

// ---------------- layer 2: out[token] = (h @ w2t[e]^T + b2[e]) * w_token ----------------
// grid (MAX_TILES, 8): 128x64 tiles, double-buffered, 2-iter prefetch.
__global__ __launch_bounds__(256) void k_ffn2(
    const uint16_t* __restrict__ hbuf, const uint16_t* __restrict__ w2t,
    const float* __restrict__ b2,
    const int* __restrict__ offsets, const int* __restrict__ counts,
    const int* __restrict__ tile_e, const int* __restrict__ tile_r0,
    const int* __restrict__ perm, const float* __restrict__ wtok,
    float* __restrict__ out)
{
  int e = tile_e[blockIdx.x];
  if (e < 0) return;
  int row0 = tile_r0[blockIdx.x];
  int row_end = offsets[e] + counts[e];
  int n0 = blockIdx.y * 64;
  const uint16_t* Bt = w2t + (size_t)e * NH * DM;

  __shared__ uint16_t As[2][128 * 64];
  __shared__ uint16_t Bs[2][64 * 64];

  int tid = threadIdx.x;
  int lane = tid & 63, wid = tid >> 6;
  int wm = wid >> 1, wn = wid & 1;
  int l16 = lane & 15, quad = lane >> 4;

  int lrow = lane >> 3;
  int lsw  = (lane & 7) ^ lrow;
  const uint16_t *ga[4], *gb[2];
  int loa[4], lob[2];
  #pragma unroll
  for (int j = 0; j < 4; ++j) {
    int r = wid * 32 + j * 8;
    ga[j] = hbuf + (size_t)(row0 + r + lrow) * NH + lsw * 8;
    loa[j] = r * 64;
  }
  #pragma unroll
  for (int j = 0; j < 2; ++j) {
    int r = wid * 16 + j * 8;
    gb[j] = Bt + (size_t)(n0 + r + lrow) * NH + lsw * 8;
    lob[j] = r * 64;
  }

  #define FFN2_ISSUE(B) do { \
    _Pragma("unroll") for (int j = 0; j < 4; ++j) { gload_lds16(ga[j], As[B] + loa[j]); ga[j] += 64; } \
    _Pragma("unroll") for (int j = 0; j < 2; ++j) { gload_lds16(gb[j], Bs[B] + lob[j]); gb[j] += 64; } \
  } while (0)

  f32x4 acc[4][2] = {};

  FFN2_ISSUE(0);
  FFN2_ISSUE(1);
  #pragma unroll 2
  for (int k = 0; k < 32; ++k) {
    if (k < 31) WAIT_BARRIER(6); else WAIT_BARRIER(0);
    int b = k & 1;
    const uint16_t* Ab = As[b];
    const uint16_t* Bb = Bs[b];
    #pragma unroll
    for (int ks = 0; ks < 2; ++ks) {
      bf16x8 a[4], bb[2];
      #pragma unroll
      for (int mi = 0; mi < 4; ++mi) {
        int row = wm * 64 + mi * 16 + l16;
        a[mi] = *(const bf16x8*)(Ab + row * 64 + (((ks * 4 + quad) ^ (l16 & 7)) * 8));
      }
      #pragma unroll
      for (int ni = 0; ni < 2; ++ni) {
        int row = wn * 32 + ni * 16 + l16;
        bb[ni] = *(const bf16x8*)(Bb + row * 64 + (((ks * 4 + quad) ^ (l16 & 7)) * 8));
      }
      #pragma unroll
      for (int mi = 0; mi < 4; ++mi)
        #pragma unroll
        for (int ni = 0; ni < 2; ++ni)
          acc[mi][ni] = __builtin_amdgcn_mfma_f32_16x16x32_bf16(a[mi], bb[ni], acc[mi][ni], 0, 0, 0);
    }
    RAW_BARRIER();
    if (k < 30) { if (b) FFN2_ISSUE(1); else FFN2_ISSUE(0); }
  }

  #pragma unroll
  for (int ni = 0; ni < 2; ++ni) {
    int col = n0 + wn * 32 + ni * 16 + l16;
    float bv = b2[e * DM + col];
    #pragma unroll
    for (int mi = 0; mi < 4; ++mi) {
      int rbase = wm * 64 + mi * 16 + quad * 4;
      #pragma unroll
      for (int r = 0; r < 4; ++r) {
        int grow = row0 + rbase + r;
        if (grow < row_end) {
          int tk = perm[grow];
          float wt = wtok[tk];
          out[(size_t)tk * DM + col] = (acc[mi][ni][r] + bv) * wt;
        }
      }
    }
  }
}

extern "C" void kernel_launch(void* const* d_in, const int* in_sizes, int n_in,
                              void* d_out, int out_size, void* d_ws, size_t ws_size,
                              hipStream_t stream)
{
  const float* x  = (const float*)d_in[0];
  const float* u  = (const float*)d_in[1];
  const float* rw = (const float*)d_in[2];
  const float* rb = (const float*)d_in[3];
  const float* w1 = (const float*)d_in[4];
  const float* b1 = (const float*)d_in[5];
  const float* w2 = (const float*)d_in[6];
  const float* b2 = (const float*)d_in[7];
  float* out = (float*)d_out;

  char* ws = (char*)d_ws;
  int*      counts    = (int*)(ws + WS_COUNTS);
  int*      cursors   = (int*)(ws + WS_CURSORS);
  int*      offsets   = (int*)(ws + WS_OFFSETS);
  int*      tile_e    = (int*)(ws + WS_TILE_E);
  int*      tile_r0   = (int*)(ws + WS_TILE_R0);
  int*      expert_of = (int*)(ws + WS_EXP);
  float*    wtok      = (float*)(ws + WS_WTOK);
  int*      perm      = (int*)(ws + WS_PERM);
  float*    imp_sh    = (float*)(ws + WS_PERM);   // overlay: read by aux BEFORE scatter writes perm
  uint16_t* Xg        = (uint16_t*)(ws + WS_XG);
  uint16_t* hbuf      = (uint16_t*)(ws + WS_H);
  uint16_t* w1t       = (uint16_t*)(ws + WS_W1T);
  uint16_t* w2t       = (uint16_t*)(ws + WS_W2T);

  hipMemsetAsync(d_ws, 0, 128, stream);
  hipMemsetAsync(ws + WS_PERM, 0, 256, stream);   // imp shards
  k_transpose_bf16<<<dim3(NH / 64, DM / 64, NE), 256, 0, stream>>>(w1, w1t, DM, NH);
  k_transpose_bf16<<<dim3(DM / 64, NH / 64, NE), 256, 0, stream>>>(w2, w2t, NH, DM);
  k_router<<<NUM_TOK / 4, 256, 0, stream>>>(x, u, rw, rb, counts, imp_sh, expert_of, wtok);
  k_aux_offsets<<<1, 64, 0, stream>>>(counts, imp_sh, offsets, out + (size_t)NUM_TOK * DM, tile_e, tile_r0);
  k_scatter<<<NUM_TOK / 256, 256, 0, stream>>>(expert_of, offsets, cursors, perm);
  k_gather<<<NUM_TOK, 64, 0, stream>>>(x, perm, Xg);
  k_ffn1<<<dim3(MAX_TILES, 16), 256, 0, stream>>>(Xg, w1t, b1, offsets, counts, tile_e, tile_r0, hbuf);
  k_ffn2<<<dim3(MAX_TILES, 8), 256, 0, stream>>>(hbuf, w2t, b2, offsets, counts, tile_e, tile_r0, perm, wtok, out);
}

// Round 8
// 316.909 us; speedup vs baseline: 1.3266x; 1.3266x over previous
//
#include <hip/hip_runtime.h>
#include <stdint.h>
#include <math.h>

#define NUM_TOK 8192
#define DM 512
#define NE 8
#define NH 2048
#define MAX_TILES 72
#define NBLK 32        // routing blocks of 256 tokens

typedef float f32x4 __attribute__((ext_vector_type(4)));
typedef __bf16 bf16x8 __attribute__((ext_vector_type(8)));

// ws layout (bytes)
#define WS_COUNTS   0                 // int[8]
#define WS_OFFSETS  64                // int[8]
#define WS_IMP      96                // float[8]
#define WS_TILE_E   128               // int[72]
#define WS_TILE_R0  416               // int[72]
#define WS_EXP      704               // int[8192]
#define WS_WTOK     33472             // float[8192]
#define WS_PERM     66240             // int[8192]
#define WS_XG       99008             // bf16 (8192+128) x 512; probs overlaid (router->postroute)
#define WS_H        8618688           // bf16 (8192+128) x 2048; rank/hist/base overlaid (pre-ffn1)
#define WS_W1T      42697408          // bf16 [8][2048][512]
#define WS_W2T      59474624          // bf16 [8][512][2048]
// overlays
#define WS_PROBS    WS_XG             // float[8192][8], dead before k_gather writes Xg
#define WS_RANK     WS_H              // int[8192], dead before k_ffn1 writes hbuf
#define WS_BHIST    (WS_H + 32768)    // int[32][8]
#define WS_BBASE    (WS_H + 33792)    // int[32][8]

__device__ __forceinline__ uint16_t f2bf(float f) {
  union { float f; uint32_t u; } c; c.f = f;
  return (uint16_t)((c.u + 0x7FFFu + ((c.u >> 16) & 1u)) >> 16);
}

__device__ __forceinline__ float gelu_fast(float v) {
  float z = 1.5957691216f * v * (1.0f + 0.044715f * v * v);
  float em = __expf(-z);
  return v / (1.0f + em);
}

__device__ __forceinline__ void gload_lds16(const void* g, void* l) {
  __builtin_amdgcn_global_load_lds(
      (const __attribute__((address_space(1))) uint32_t*)g,
      (__attribute__((address_space(3))) uint32_t*)l, 16, 0, 0);
}

#define WAIT_BARRIER(N) asm volatile("s_waitcnt vmcnt(" #N ")\ns_barrier" ::: "memory")
#define RAW_BARRIER()   asm volatile("s_barrier" ::: "memory")

// ---------------- router: one wave per token, fp64, NO atomics ----------------
__global__ __launch_bounds__(256) void k_router(
    const float* __restrict__ x, const float* __restrict__ u,
    const float* __restrict__ rw, const float* __restrict__ rb,
    int* __restrict__ expert_of, float* __restrict__ wtok,
    float* __restrict__ probs)
{
  int wv = threadIdx.x >> 6, lane = threadIdx.x & 63;
  int t = blockIdx.x * 4 + wv;

  const float4* xr = (const float4*)(x + (size_t)t * DM + lane * 8);
  float4 xa = xr[0], xb = xr[1];
  float xs[8] = {xa.x, xa.y, xa.z, xa.w, xb.x, xb.y, xb.z, xb.w};

  double acc[NE];
  #pragma unroll
  for (int e = 0; e < NE; ++e) acc[e] = 0.0;
  #pragma unroll
  for (int j = 0; j < 8; ++j) {
    const float4* rr = (const float4*)(rw + (size_t)(lane * 8 + j) * NE);
    float4 r0 = rr[0], r1 = rr[1];
    double xv = (double)xs[j];
    acc[0] += xv * (double)r0.x; acc[1] += xv * (double)r0.y;
    acc[2] += xv * (double)r0.z; acc[3] += xv * (double)r0.w;
    acc[4] += xv * (double)r1.x; acc[5] += xv * (double)r1.y;
    acc[6] += xv * (double)r1.z; acc[7] += xv * (double)r1.w;
  }
  #pragma unroll
  for (int m = 1; m < 64; m <<= 1) {
    #pragma unroll
    for (int e = 0; e < NE; ++e) acc[e] += __shfl_xor(acc[e], m, 64);
  }
  double lg[NE];
  #pragma unroll
  for (int e = 0; e < NE; ++e) lg[e] = acc[e] + (double)rb[e];

  int le = lane & 7;
  double lgE = le == 0 ? lg[0] : le == 1 ? lg[1] : le == 2 ? lg[2] : le == 3 ? lg[3]
             : le == 4 ? lg[4] : le == 5 ? lg[5] : le == 6 ? lg[6] : lg[7];

  double yE = -1e300;
  if (lane < 8) {
    double uv = (double)u[(size_t)t * NE + lane];
    double g = -log(-log(uv) + 1e-10);
    yE = lgE + g;
  }
  double ymax = yE;
  #pragma unroll
  for (int m = 1; m < 8; m <<= 1) ymax = fmax(ymax, __shfl_xor(ymax, m, 64));
  double ex = (lane < 8) ? exp(yE - ymax) : 0.0;
  double s = ex;
  #pragma unroll
  for (int m = 1; m < 8; m <<= 1) s += __shfl_xor(s, m, 64);
  double p = 1.0 / s;
  unsigned long long mk = __ballot(lane < 8 && yE == ymax);
  int sel = __ffsll(mk) - 1;

  double lm = lgE;
  #pragma unroll
  for (int m = 1; m < 8; m <<= 1) lm = fmax(lm, __shfl_xor(lm, m, 64));
  double pr = exp(lgE - lm);
  double ssum = pr;
  #pragma unroll
  for (int m = 1; m < 8; m <<= 1) ssum += __shfl_xor(ssum, m, 64);

  if (lane < 8) probs[(size_t)t * NE + lane] = (float)(pr / ssum);
  if (lane == 0) {
    expert_of[t] = sel;
    wtok[t] = (float)((1.0 - p) + p);
  }
}

// ---------------- postroute: ballot histogram + local ranks + importance ----------------
// grid NBLK x 256. Zero per-token atomics; 8 atomics/block for importance.
__global__ __launch_bounds__(256) void k_postroute(
    const int* __restrict__ expert_of, const float* __restrict__ probs,
    int* __restrict__ rank_local, int* __restrict__ block_hist,
    float* __restrict__ imp)
{
  __shared__ int whist[4][8];
  __shared__ float simp[4][8];
  int tid = threadIdx.x, lane = tid & 63, wid = tid >> 6;
  int t = blockIdx.x * 256 + tid;
  int sel = expert_of[t];

  int cnt[8]; int lrank = 0;
  unsigned long long below = (1ull << lane) - 1ull;
  #pragma unroll
  for (int e = 0; e < 8; ++e) {
    unsigned long long m = __ballot(sel == e);
    cnt[e] = (int)__popcll(m);
    if (e == sel) lrank = (int)__popcll(m & below);
  }
  if (lane == 0) {
    #pragma unroll
    for (int e = 0; e < 8; ++e) whist[wid][e] = cnt[e];
  }

  const float4* pp = (const float4*)(probs + (size_t)t * NE);
  float4 pa = pp[0], pb = pp[1];
  float ps[8] = {pa.x, pa.y, pa.z, pa.w, pb.x, pb.y, pb.z, pb.w};
  #pragma unroll
  for (int j = 0; j < 8; ++j) {
    float v = ps[j];
    #pragma unroll
    for (int m = 1; m < 64; m <<= 1) v += __shfl_xor(v, m, 64);
    if (lane == 0) simp[wid][j] = v;
  }
  __syncthreads();

  int base = 0;
  #pragma unroll
  for (int w = 0; w < 4; ++w) if (w < wid) base += whist[w][sel];
  rank_local[t] = base + lrank;

  if (tid < 8) {
    int c = whist[0][tid] + whist[1][tid] + whist[2][tid] + whist[3][tid];
    block_hist[blockIdx.x * 8 + tid] = c;
    float sv = simp[0][tid] + simp[1][tid] + simp[2][tid] + simp[3][tid];
    atomicAdd(&imp[tid], sv);
  }
}

// ---------------- offsets + block bases + aux loss + tile table ----------------
__global__ void k_offsets(const int* __restrict__ block_hist, const float* __restrict__ imp,
                          int* __restrict__ counts, int* __restrict__ offsets,
                          int* __restrict__ block_base, float* __restrict__ aux_out,
                          int* __restrict__ tile_e, int* __restrict__ tile_r0)
{
  if (threadIdx.x == 0) {
    int c[8];
    for (int e = 0; e < NE; ++e) {
      c[e] = 0;
      for (int b = 0; b < NBLK; ++b) c[e] += block_hist[b * 8 + e];
    }
    int o = 0;
    for (int e = 0; e < NE; ++e) { offsets[e] = o; counts[e] = c[e]; o += c[e]; }
    for (int e = 0; e < NE; ++e) {
      int run = offsets[e];
      for (int b = 0; b < NBLK; ++b) { block_base[b * 8 + e] = run; run += block_hist[b * 8 + e]; }
    }
    float a = 0.0f;
    for (int e = 0; e < NE; ++e) {
      float dv = imp[e] / 8192.0f - 0.125f;
      a += dv * dv;
    }
    aux_out[0] = a / 8.0f;
    int nt = 0;
    for (int e = 0; e < NE; ++e) {
      int ntile = (c[e] + 127) >> 7;
      for (int j = 0; j < ntile; ++j) { tile_e[nt] = e; tile_r0[nt] = offsets[e] + j * 128; ++nt; }
    }
    for (int i = nt; i < MAX_TILES; ++i) { tile_e[i] = -1; tile_r0[i] = 0; }
  }
}

// ---------------- scatter (atomic-free): perm[base + rank] = t ----------------
__global__ __launch_bounds__(256) void k_scatter2(
    const int* __restrict__ expert_of, const int* __restrict__ rank_local,
    const int* __restrict__ block_base, int* __restrict__ perm)
{
  int t = blockIdx.x * 256 + threadIdx.x;
  int e = expert_of[t];
  perm[block_base[blockIdx.x * 8 + e] + rank_local[t]] = t;
}

// ---------------- gather x rows into sorted bf16 Xg ----------------
__global__ __launch_bounds__(64) void k_gather(
    const float* __restrict__ x, const int* __restrict__ perm, uint16_t* __restrict__ Xg)
{
  int r = blockIdx.x;
  int lane = threadIdx.x;
  int t = perm[r];
  const float4* src = (const float4*)(x + (size_t)t * DM);
  float4 a = src[lane * 2];
  float4 b = src[lane * 2 + 1];
  uint32_t p0 = (uint32_t)f2bf(a.x) | ((uint32_t)f2bf(a.y) << 16);
  uint32_t p1 = (uint32_t)f2bf(a.z) | ((uint32_t)f2bf(a.w) << 16);
  uint32_t p2 = (uint32_t)f2bf(b.x) | ((uint32_t)f2bf(b.y) << 16);
  uint32_t p3 = (uint32_t)f2bf(b.z) | ((uint32_t)f2bf(b.w) << 16);
  uint4 v = make_uint4(p0, p1, p2, p3);
  ((uint4*)(Xg + (size_t)r * DM))[lane] = v;
}

// ---------------- weight transpose+convert: src [e][K][N] f32 -> dst [e][N][K] bf16 ----------------
__global__ __launch_bounds__(256) void k_transpose_bf16(
    const float* __restrict__ src, uint16_t* __restrict__ dst, int K, int N)
{
  __shared__ float T[64][65];
  int e = blockIdx.z;
  const float* s = src + (size_t)e * K * N;
  uint16_t* d = dst + (size_t)e * K * N;
  int n0 = blockIdx.x * 64, k0 = blockIdx.y * 64;
  int tid = threadIdx.x;
  int tr = tid >> 4;
  int tc = (tid & 15) * 4;
  #pragma unroll
  for (int p = 0; p < 4; ++p) {
    int k = tr + p * 16;
    float4 v = *(const float4*)(s + (size_t)(k0 + k) * N + n0 + tc);
    T[k][tc] = v.x; T[k][tc + 1] = v.y; T[k][tc + 2] = v.z; T[k][tc + 3] = v.w;
  }
  __syncthreads();
  #pragma unroll
  for (int p = 0; p < 2; ++p) {
    int slot = p * 256 + tid;
    int n = slot >> 3;
    int c = (slot & 7) * 8;
    uint16_t tmp[8];
    #pragma unroll
    for (int j = 0; j < 8; ++j) tmp[j] = f2bf(T[c + j][n]);
    *(uint4*)(d + (size_t)(n0 + n) * K + k0 + c) = *(uint4*)tmp;
  }
}

__device__ __forceinline__ void mfma_128x128(
    const uint16_t* Asb, const uint16_t* Bsb, f32x4 (&acc)[4][4],
    int wm, int wn, int l16, int quad)
{
  #pragma unroll
  for (int ks = 0; ks < 2; ++ks) {
    bf16x8 a[4], b[4];
    #pragma unroll
    for (int mi = 0; mi < 4; ++mi) {
      int row = wm * 64 + mi * 16 + l16;
      a[mi] = *(const bf16x8*)(Asb + row * 64 + (((ks * 4 + quad) ^ (l16 & 7)) * 8));
    }
    #pragma unroll
    for (int ni = 0; ni < 4; ++ni) {
      int row = wn * 64 + ni * 16 + l16;
      b[ni] = *(const bf16x8*)(Bsb + row * 64 + (((ks * 4 + quad) ^ (l16 & 7)) * 8));
    }
    #pragma unroll
    for (int mi = 0; mi < 4; ++mi)
      #pragma unroll
      for (int ni = 0; ni < 4; ++ni)
        acc[mi][ni] = __builtin_amdgcn_mfma_f32_16x16x32_bf16(a[mi], b[ni], acc[mi][ni], 0, 0, 0);
  }
}

// ---------------- layer 1: h = gelu(Xg @ w1t[e]^T + b1[e]) ----------------
__global__ __launch_bounds__(256) void k_ffn1(
    const uint16_t* __restrict__ Xg, const uint16_t* __restrict__ w1t,
    const float* __restrict__ b1,
    const int* __restrict__ offsets, const int* __restrict__ counts,
    const int* __restrict__ tile_e, const int* __restrict__ tile_r0,
    uint16_t* __restrict__ hbuf)
{
  int e = tile_e[blockIdx.x];
  if (e < 0) return;
  int row0 = tile_r0[blockIdx.x];
  int row_end = offsets[e] + counts[e];
  int n0 = blockIdx.y * 128;
  const uint16_t* Bt = w1t + (size_t)e * DM * NH;

  __shared__ uint16_t As[2][128 * 64];
  __shared__ uint16_t Bs[2][128 * 64];

  int tid = threadIdx.x;
  int lane = tid & 63, wid = tid >> 6;
  int wm = wid >> 1, wn = wid & 1;
  int l16 = lane & 15, quad = lane >> 4;

  int lrow = lane >> 3;
  int lsw  = (lane & 7) ^ lrow;
  const uint16_t *ga[4], *gb[4];
  int lo[4];
  #pragma unroll
  for (int j = 0; j < 4; ++j) {
    int r = wid * 32 + j * 8;
    ga[j] = Xg + (size_t)(row0 + r + lrow) * DM + lsw * 8;
    gb[j] = Bt + (size_t)(n0 + r + lrow) * DM + lsw * 8;
    lo[j] = r * 64;
  }

  #define FFN1_ISSUE(B) do { \
    _Pragma("unroll") for (int j = 0; j < 4; ++j) { gload_lds16(ga[j], As[B] + lo[j]); ga[j] += 64; } \
    _Pragma("unroll") for (int j = 0; j < 4; ++j) { gload_lds16(gb[j], Bs[B] + lo[j]); gb[j] += 64; } \
  } while (0)

  f32x4 acc[4][4] = {};

  FFN1_ISSUE(0);
  FFN1_ISSUE(1);
  #pragma unroll 2
  for (int k = 0; k < 8; ++k) {
    if (k < 7) WAIT_BARRIER(8); else WAIT_BARRIER(0);
    int b = k & 1;
    mfma_128x128(As[b], Bs[b], acc, wm, wn, l16, quad);
    RAW_BARRIER();
    if (k < 6) { if (b) FFN1_ISSUE(1); else FFN1_ISSUE(0); }
  }

  #pragma unroll
  for (int ni = 0; ni < 4; ++ni) {
    int col = n0 + wn * 64 + ni * 16 + l16;
    float bv = b1[e * NH + col];
    #pragma unroll
    for (int mi = 0; mi < 4; ++mi) {
      int rbase = wm * 64 + mi * 16 + quad * 4;
      #pragma unroll
      for (int r = 0; r < 4; ++r) {
        int grow = row0 + rbase + r;
        if (grow < row_end) {
          float v = acc[mi][ni][r] + bv;
          hbuf[(size_t)grow * NH + col] = f2bf(gelu_fast(v));
        }
      }
    }
  }
}

// ---------------- layer 2: out[token] = (h @ w2t[e]^T + b2[e]) * w_token ----------------
__global__ __launch_bounds__(256) void k_ffn2(
    const uint16_t* __restrict__ hbuf, const uint16_t* __restrict__ w2t,
    const float* __restrict__ b2,
    const int* __restrict__ offsets, const int* __restrict__ counts,
    const int* __restrict__ tile_e, const int* __restrict__ tile_r0,
    const int* __restrict__ perm, const float* __restrict__ wtok,
    float* __restrict__ out)
{
  int e = tile_e[blockIdx.x];
  if (e < 0) return;
  int row0 = tile_r0[blockIdx.x];
  int row_end = offsets[e] + counts[e];
  int n0 = blockIdx.y * 64;
  const uint16_t* Bt = w2t + (size_t)e * NH * DM;

  __shared__ uint16_t As[2][128 * 64];
  __shared__ uint16_t Bs[2][64 * 64];

  int tid = threadIdx.x;
  int lane = tid & 63, wid = tid >> 6;
  int wm = wid >> 1, wn = wid & 1;
  int l16 = lane & 15, quad = lane >> 4;

  int lrow = lane >> 3;
  int lsw  = (lane & 7) ^ lrow;
  const uint16_t *ga[4], *gb[2];
  int loa[4], lob[2];
  #pragma unroll
  for (int j = 0; j < 4; ++j) {
    int r = wid * 32 + j * 8;
    ga[j] = hbuf + (size_t)(row0 + r + lrow) * NH + lsw * 8;
    loa[j] = r * 64;
  }
  #pragma unroll
  for (int j = 0; j < 2; ++j) {
    int r = wid * 16 + j * 8;
    gb[j] = Bt + (size_t)(n0 + r + lrow) * NH + lsw * 8;
    lob[j] = r * 64;
  }

  #define FFN2_ISSUE(B) do { \
    _Pragma("unroll") for (int j = 0; j < 4; ++j) { gload_lds16(ga[j], As[B] + loa[j]); ga[j] += 64; } \
    _Pragma("unroll") for (int j = 0; j < 2; ++j) { gload_lds16(gb[j], Bs[B] + lob[j]); gb[j] += 64; } \
  } while (0)

  f32x4 acc[4][2] = {};

  FFN2_ISSUE(0);
  FFN2_ISSUE(1);
  #pragma unroll 2
  for (int k = 0; k < 32; ++k) {
    if (k < 31) WAIT_BARRIER(6); else WAIT_BARRIER(0);
    int b = k & 1;
    const uint16_t* Ab = As[b];
    const uint16_t* Bb = Bs[b];
    #pragma unroll
    for (int ks = 0; ks < 2; ++ks) {
      bf16x8 a[4], bb[2];
      #pragma unroll
      for (int mi = 0; mi < 4; ++mi) {
        int row = wm * 64 + mi * 16 + l16;
        a[mi] = *(const bf16x8*)(Ab + row * 64 + (((ks * 4 + quad) ^ (l16 & 7)) * 8));
      }
      #pragma unroll
      for (int ni = 0; ni < 2; ++ni) {
        int row = wn * 32 + ni * 16 + l16;
        bb[ni] = *(const bf16x8*)(Bb + row * 64 + (((ks * 4 + quad) ^ (l16 & 7)) * 8));
      }
      #pragma unroll
      for (int mi = 0; mi < 4; ++mi)
        #pragma unroll
        for (int ni = 0; ni < 2; ++ni)
          acc[mi][ni] = __builtin_amdgcn_mfma_f32_16x16x32_bf16(a[mi], bb[ni], acc[mi][ni], 0, 0, 0);
    }
    RAW_BARRIER();
    if (k < 30) { if (b) FFN2_ISSUE(1); else FFN2_ISSUE(0); }
  }

  #pragma unroll
  for (int ni = 0; ni < 2; ++ni) {
    int col = n0 + wn * 32 + ni * 16 + l16;
    float bv = b2[e * DM + col];
    #pragma unroll
    for (int mi = 0; mi < 4; ++mi) {
      int rbase = wm * 64 + mi * 16 + quad * 4;
      #pragma unroll
      for (int r = 0; r < 4; ++r) {
        int grow = row0 + rbase + r;
        if (grow < row_end) {
          int tk = perm[grow];
          float wt = wtok[tk];
          out[(size_t)tk * DM + col] = (acc[mi][ni][r] + bv) * wt;
        }
      }
    }
  }
}

extern "C" void kernel_launch(void* const* d_in, const int* in_sizes, int n_in,
                              void* d_out, int out_size, void* d_ws, size_t ws_size,
                              hipStream_t stream)
{
  const float* x  = (const float*)d_in[0];
  const float* u  = (const float*)d_in[1];
  const float* rw = (const float*)d_in[2];
  const float* rb = (const float*)d_in[3];
  const float* w1 = (const float*)d_in[4];
  const float* b1 = (const float*)d_in[5];
  const float* w2 = (const float*)d_in[6];
  const float* b2 = (const float*)d_in[7];
  float* out = (float*)d_out;

  char* ws = (char*)d_ws;
  int*      counts     = (int*)(ws + WS_COUNTS);
  int*      offsets    = (int*)(ws + WS_OFFSETS);
  float*    imp        = (float*)(ws + WS_IMP);
  int*      tile_e     = (int*)(ws + WS_TILE_E);
  int*      tile_r0    = (int*)(ws + WS_TILE_R0);
  int*      expert_of  = (int*)(ws + WS_EXP);
  float*    wtok       = (float*)(ws + WS_WTOK);
  int*      perm       = (int*)(ws + WS_PERM);
  float*    probs      = (float*)(ws + WS_PROBS);
  int*      rank_local = (int*)(ws + WS_RANK);
  int*      block_hist = (int*)(ws + WS_BHIST);
  int*      block_base = (int*)(ws + WS_BBASE);
  uint16_t* Xg         = (uint16_t*)(ws + WS_XG);
  uint16_t* hbuf       = (uint16_t*)(ws + WS_H);
  uint16_t* w1t        = (uint16_t*)(ws + WS_W1T);
  uint16_t* w2t        = (uint16_t*)(ws + WS_W2T);

  hipMemsetAsync(d_ws, 0, 128, stream);   // zeroes imp (and counts/offsets, rewritten anyway)
  k_transpose_bf16<<<dim3(NH / 64, DM / 64, NE), 256, 0, stream>>>(w1, w1t, DM, NH);
  k_transpose_bf16<<<dim3(DM / 64, NH / 64, NE), 256, 0, stream>>>(w2, w2t, NH, DM);
  k_router<<<NUM_TOK / 4, 256, 0, stream>>>(x, u, rw, rb, expert_of, wtok, probs);
  k_postroute<<<NBLK, 256, 0, stream>>>(expert_of, probs, rank_local, block_hist, imp);
  k_offsets<<<1, 64, 0, stream>>>(block_hist, imp, counts, offsets, block_base,
                                  out + (size_t)NUM_TOK * DM, tile_e, tile_r0);
  k_scatter2<<<NBLK, 256, 0, stream>>>(expert_of, rank_local, block_base, perm);
  k_gather<<<NUM_TOK, 64, 0, stream>>>(x, perm, Xg);
  k_ffn1<<<dim3(MAX_TILES, 16), 256, 0, stream>>>(Xg, w1t, b1, offsets, counts, tile_e, tile_r0, hbuf);
  k_ffn2<<<dim3(MAX_TILES, 8), 256, 0, stream>>>(hbuf, w2t, b2, offsets, counts, tile_e, tile_r0, perm, wtok, out);
}

// Round 9
// 293.165 us; speedup vs baseline: 1.4341x; 1.0810x over previous
//
#include <hip/hip_runtime.h>
#include <stdint.h>
#include <math.h>

#define NUM_TOK 8192
#define DM 512
#define NE 8
#define NH 2048
#define MAX_TILES 72
#define NBLK 32        // routing blocks of 256 tokens

typedef float f32x4 __attribute__((ext_vector_type(4)));
typedef __bf16 bf16x8 __attribute__((ext_vector_type(8)));

// ws layout (bytes)
#define WS_COUNTS   0                 // int[8]
#define WS_OFFSETS  64                // int[8]
#define WS_IMP      96                // float[8]
#define WS_TILE_E   128               // int[72]
#define WS_TILE_R0  416               // int[72]
#define WS_EXP      704               // int[8192]
#define WS_WTOK     33472             // float[8192]
#define WS_PERM     66240             // int[8192]
#define WS_XG       99008             // bf16 (8192+128) x 512; probs overlaid (router->postroute)
#define WS_H        8618688           // bf16 (8192+128) x 2048; rank/hist/base overlaid (pre-ffn1)
#define WS_W1T      42697408          // bf16 [8][2048][512]
#define WS_W2T      59474624          // bf16 [8][512][2048]
// overlays
#define WS_PROBS    WS_XG             // float[8192][8], dead before k_gather writes Xg
#define WS_RANK     WS_H              // int[8192], dead before k_ffn1 writes hbuf
#define WS_BHIST    (WS_H + 32768)    // int[32][8]
#define WS_BBASE    (WS_H + 33792)    // int[32][8]

__device__ __forceinline__ uint16_t f2bf(float f) {
  union { float f; uint32_t u; } c; c.f = f;
  return (uint16_t)((c.u + 0x7FFFu + ((c.u >> 16) & 1u)) >> 16);
}

__device__ __forceinline__ float gelu_fast(float v) {
  float z = 1.5957691216f * v * (1.0f + 0.044715f * v * v);
  float em = __expf(-z);
  return v / (1.0f + em);
}

__device__ __forceinline__ void gload_lds16(const void* g, void* l) {
  __builtin_amdgcn_global_load_lds(
      (const __attribute__((address_space(1))) uint32_t*)g,
      (__attribute__((address_space(3))) uint32_t*)l, 16, 0, 0);
}

#define WAIT_BARRIER(N) asm volatile("s_waitcnt vmcnt(" #N ")\ns_barrier" ::: "memory")
#define RAW_BARRIER()   asm volatile("s_barrier" ::: "memory")

// ---------------- router: one wave per token, fp64, NO atomics ----------------
__global__ __launch_bounds__(256) void k_router(
    const float* __restrict__ x, const float* __restrict__ u,
    const float* __restrict__ rw, const float* __restrict__ rb,
    int* __restrict__ expert_of, float* __restrict__ wtok,
    float* __restrict__ probs)
{
  int wv = threadIdx.x >> 6, lane = threadIdx.x & 63;
  int t = blockIdx.x * 4 + wv;

  const float4* xr = (const float4*)(x + (size_t)t * DM + lane * 8);
  float4 xa = xr[0], xb = xr[1];
  float xs[8] = {xa.x, xa.y, xa.z, xa.w, xb.x, xb.y, xb.z, xb.w};

  double acc[NE];
  #pragma unroll
  for (int e = 0; e < NE; ++e) acc[e] = 0.0;
  #pragma unroll
  for (int j = 0; j < 8; ++j) {
    const float4* rr = (const float4*)(rw + (size_t)(lane * 8 + j) * NE);
    float4 r0 = rr[0], r1 = rr[1];
    double xv = (double)xs[j];
    acc[0] += xv * (double)r0.x; acc[1] += xv * (double)r0.y;
    acc[2] += xv * (double)r0.z; acc[3] += xv * (double)r0.w;
    acc[4] += xv * (double)r1.x; acc[5] += xv * (double)r1.y;
    acc[6] += xv * (double)r1.z; acc[7] += xv * (double)r1.w;
  }
  #pragma unroll
  for (int m = 1; m < 64; m <<= 1) {
    #pragma unroll
    for (int e = 0; e < NE; ++e) acc[e] += __shfl_xor(acc[e], m, 64);
  }
  double lg[NE];
  #pragma unroll
  for (int e = 0; e < NE; ++e) lg[e] = acc[e] + (double)rb[e];

  int le = lane & 7;
  double lgE = le == 0 ? lg[0] : le == 1 ? lg[1] : le == 2 ? lg[2] : le == 3 ? lg[3]
             : le == 4 ? lg[4] : le == 5 ? lg[5] : le == 6 ? lg[6] : lg[7];

  double yE = -1e300;
  if (lane < 8) {
    double uv = (double)u[(size_t)t * NE + lane];
    double g = -log(-log(uv) + 1e-10);
    yE = lgE + g;
  }
  double ymax = yE;
  #pragma unroll
  for (int m = 1; m < 8; m <<= 1) ymax = fmax(ymax, __shfl_xor(ymax, m, 64));
  double ex = (lane < 8) ? exp(yE - ymax) : 0.0;
  double s = ex;
  #pragma unroll
  for (int m = 1; m < 8; m <<= 1) s += __shfl_xor(s, m, 64);
  double p = 1.0 / s;
  unsigned long long mk = __ballot(lane < 8 && yE == ymax);
  int sel = __ffsll(mk) - 1;

  double lm = lgE;
  #pragma unroll
  for (int m = 1; m < 8; m <<= 1) lm = fmax(lm, __shfl_xor(lm, m, 64));
  double pr = exp(lgE - lm);
  double ssum = pr;
  #pragma unroll
  for (int m = 1; m < 8; m <<= 1) ssum += __shfl_xor(ssum, m, 64);

  if (lane < 8) probs[(size_t)t * NE + lane] = (float)(pr / ssum);
  if (lane == 0) {
    expert_of[t] = sel;
    wtok[t] = (float)((1.0 - p) + p);
  }
}

// ---------------- postroute: ballot histogram + local ranks + importance ----------------
__global__ __launch_bounds__(256) void k_postroute(
    const int* __restrict__ expert_of, const float* __restrict__ probs,
    int* __restrict__ rank_local, int* __restrict__ block_hist,
    float* __restrict__ imp)
{
  __shared__ int whist[4][8];
  __shared__ float simp[4][8];
  int tid = threadIdx.x, lane = tid & 63, wid = tid >> 6;
  int t = blockIdx.x * 256 + tid;
  int sel = expert_of[t];

  int cnt[8]; int lrank = 0;
  unsigned long long below = (1ull << lane) - 1ull;
  #pragma unroll
  for (int e = 0; e < 8; ++e) {
    unsigned long long m = __ballot(sel == e);
    cnt[e] = (int)__popcll(m);
    if (e == sel) lrank = (int)__popcll(m & below);
  }
  if (lane == 0) {
    #pragma unroll
    for (int e = 0; e < 8; ++e) whist[wid][e] = cnt[e];
  }

  const float4* pp = (const float4*)(probs + (size_t)t * NE);
  float4 pa = pp[0], pb = pp[1];
  float ps[8] = {pa.x, pa.y, pa.z, pa.w, pb.x, pb.y, pb.z, pb.w};
  #pragma unroll
  for (int j = 0; j < 8; ++j) {
    float v = ps[j];
    #pragma unroll
    for (int m = 1; m < 64; m <<= 1) v += __shfl_xor(v, m, 64);
    if (lane == 0) simp[wid][j] = v;
  }
  __syncthreads();

  int base = 0;
  #pragma unroll
  for (int w = 0; w < 4; ++w) if (w < wid) base += whist[w][sel];
  rank_local[t] = base + lrank;

  if (tid < 8) {
    int c = whist[0][tid] + whist[1][tid] + whist[2][tid] + whist[3][tid];
    block_hist[blockIdx.x * 8 + tid] = c;
    float sv = simp[0][tid] + simp[1][tid] + simp[2][tid] + simp[3][tid];
    atomicAdd(&imp[tid], sv);
  }
}

// ---------------- offsets + block bases + aux + tile table (PARALLEL loads) ----------------
// one block of 256 threads: coalesced hist load -> LDS, parallel base computation.
__global__ __launch_bounds__(256) void k_offsets(
    const int* __restrict__ block_hist, const float* __restrict__ imp,
    int* __restrict__ counts, int* __restrict__ offsets,
    int* __restrict__ block_base, float* __restrict__ aux_out,
    int* __restrict__ tile_e, int* __restrict__ tile_r0)
{
  __shared__ int sh[NBLK * 8];      // [b][e]
  __shared__ int scnt[8];
  __shared__ int soff[8];
  __shared__ float simp[8];
  int tid = threadIdx.x;

  sh[tid] = block_hist[tid];        // 256 coalesced loads, fully parallel
  if (tid < 8) simp[tid] = imp[tid];
  __syncthreads();

  if (tid < 8) {                    // per-expert counts (LDS, parallel over e)
    int c = 0;
    #pragma unroll
    for (int b = 0; b < NBLK; ++b) c += sh[b * 8 + tid];
    scnt[tid] = c;
    counts[tid] = c;
  }
  __syncthreads();

  if (tid == 0) {                   // tiny serial prefix + aux + tile table (all LDS-fed)
    int o = 0;
    #pragma unroll
    for (int e = 0; e < NE; ++e) { soff[e] = o; offsets[e] = o; o += scnt[e]; }
    float a = 0.0f;
    #pragma unroll
    for (int e = 0; e < NE; ++e) {
      float dv = simp[e] / 8192.0f - 0.125f;
      a += dv * dv;
    }
    aux_out[0] = a / 8.0f;
    int nt = 0;
    for (int e = 0; e < NE; ++e) {
      int ntile = (scnt[e] + 127) >> 7;
      for (int j = 0; j < ntile; ++j) { tile_e[nt] = e; tile_r0[nt] = soff[e] + j * 128; ++nt; }
    }
    for (int i = nt; i < MAX_TILES; ++i) { tile_e[i] = -1; tile_r0[i] = 0; }
  }
  __syncthreads();

  // block_base[b][e] = offsets[e] + sum_{b'<b} hist[b'][e]; thread (b,e) in parallel
  int b = tid >> 3, e = tid & 7;
  int run = soff[e];
  for (int bp = 0; bp < b; ++bp) run += sh[bp * 8 + e];
  block_base[tid] = run;
}

// ---------------- scatter (atomic-free): perm[base + rank] = t ----------------
__global__ __launch_bounds__(256) void k_scatter2(
    const int* __restrict__ expert_of, const int* __restrict__ rank_local,
    const int* __restrict__ block_base, int* __restrict__ perm)
{
  int t = blockIdx.x * 256 + threadIdx.x;
  int e = expert_of[t];
  perm[block_base[blockIdx.x * 8 + e] + rank_local[t]] = t;
}

// ---------------- gather x rows into sorted bf16 Xg ----------------
__global__ __launch_bounds__(64) void k_gather(
    const float* __restrict__ x, const int* __restrict__ perm, uint16_t* __restrict__ Xg)
{
  int r = blockIdx.x;
  int lane = threadIdx.x;
  int t = perm[r];
  const float4* src = (const float4*)(x + (size_t)t * DM);
  float4 a = src[lane * 2];
  float4 b = src[lane * 2 + 1];
  uint32_t p0 = (uint32_t)f2bf(a.x) | ((uint32_t)f2bf(a.y) << 16);
  uint32_t p1 = (uint32_t)f2bf(a.z) | ((uint32_t)f2bf(a.w) << 16);
  uint32_t p2 = (uint32_t)f2bf(b.x) | ((uint32_t)f2bf(b.y) << 16);
  uint32_t p3 = (uint32_t)f2bf(b.z) | ((uint32_t)f2bf(b.w) << 16);
  uint4 v = make_uint4(p0, p1, p2, p3);
  ((uint4*)(Xg + (size_t)r * DM))[lane] = v;
}

// ---------------- weight transpose+convert: src [e][K][N] f32 -> dst [e][N][K] bf16 ----------------
__global__ __launch_bounds__(256) void k_transpose_bf16(
    const float* __restrict__ src, uint16_t* __restrict__ dst, int K, int N)
{
  __shared__ float T[64][65];
  int e = blockIdx.z;
  const float* s = src + (size_t)e * K * N;
  uint16_t* d = dst + (size_t)e * K * N;
  int n0 = blockIdx.x * 64, k0 = blockIdx.y * 64;
  int tid = threadIdx.x;
  int tr = tid >> 4;
  int tc = (tid & 15) * 4;
  #pragma unroll
  for (int p = 0; p < 4; ++p) {
    int k = tr + p * 16;
    float4 v = *(const float4*)(s + (size_t)(k0 + k) * N + n0 + tc);
    T[k][tc] = v.x; T[k][tc + 1] = v.y; T[k][tc + 2] = v.z; T[k][tc + 3] = v.w;
  }
  __syncthreads();
  #pragma unroll
  for (int p = 0; p < 2; ++p) {
    int slot = p * 256 + tid;
    int n = slot >> 3;
    int c = (slot & 7) * 8;
    uint16_t tmp[8];
    #pragma unroll
    for (int j = 0; j < 8; ++j) tmp[j] = f2bf(T[c + j][n]);
    *(uint4*)(d + (size_t)(n0 + n) * K + k0 + c) = *(uint4*)tmp;
  }
}

__device__ __forceinline__ void mfma_128x128(
    const uint16_t* Asb, const uint16_t* Bsb, f32x4 (&acc)[4][4],
    int wm, int wn, int l16, int quad)
{
  #pragma unroll
  for (int ks = 0; ks < 2; ++ks) {
    bf16x8 a[4], b[4];
    #pragma unroll
    for (int mi = 0; mi < 4; ++mi) {
      int row = wm * 64 + mi * 16 + l16;
      a[mi] = *(const bf16x8*)(Asb + row * 64 + (((ks * 4 + quad) ^ (l16 & 7)) * 8));
    }
    #pragma unroll
    for (int ni = 0; ni < 4; ++ni) {
      int row = wn * 64 + ni * 16 + l16;
      b[ni] = *(const bf16x8*)(Bsb + row * 64 + (((ks * 4 + quad) ^ (l16 & 7)) * 8));
    }
    #pragma unroll
    for (int mi = 0; mi < 4; ++mi)
      #pragma unroll
      for (int ni = 0; ni < 4; ++ni)
        acc[mi][ni] = __builtin_amdgcn_mfma_f32_16x16x32_bf16(a[mi], b[ni], acc[mi][ni], 0, 0, 0);
  }
}

// ---------------- layer 1: h = gelu(Xg @ w1t[e]^T + b1[e]) ----------------
__global__ __launch_bounds__(256) void k_ffn1(
    const uint16_t* __restrict__ Xg, const uint16_t* __restrict__ w1t,
    const float* __restrict__ b1,
    const int* __restrict__ offsets, const int* __restrict__ counts,
    const int* __restrict__ tile_e, const int* __restrict__ tile_r0,
    uint16_t* __restrict__ hbuf)
{
  int e = tile_e[blockIdx.x];
  if (e < 0) return;
  int row0 = tile_r0[blockIdx.x];
  int row_end = offsets[e] + counts[e];
  int n0 = blockIdx.y * 128;
  const uint16_t* Bt = w1t + (size_t)e * DM * NH;

  __shared__ uint16_t As[2][128 * 64];
  __shared__ uint16_t Bs[2][128 * 64];

  int tid = threadIdx.x;
  int lane = tid & 63, wid = tid >> 6;
  int wm = wid >> 1, wn = wid & 1;
  int l16 = lane & 15, quad = lane >> 4;

  int lrow = lane >> 3;
  int lsw  = (lane & 7) ^ lrow;
  const uint16_t *ga[4], *gb[4];
  int lo[4];
  #pragma unroll
  for (int j = 0; j < 4; ++j) {
    int r = wid * 32 + j * 8;
    ga[j] = Xg + (size_t)(row0 + r + lrow) * DM + lsw * 8;
    gb[j] = Bt + (size_t)(n0 + r + lrow) * DM + lsw * 8;
    lo[j] = r * 64;
  }

  #define FFN1_ISSUE(B) do { \
    _Pragma("unroll") for (int j = 0; j < 4; ++j) { gload_lds16(ga[j], As[B] + lo[j]); ga[j] += 64; } \
    _Pragma("unroll") for (int j = 0; j < 4; ++j) { gload_lds16(gb[j], Bs[B] + lo[j]); gb[j] += 64; } \
  } while (0)

  f32x4 acc[4][4] = {};

  FFN1_ISSUE(0);
  FFN1_ISSUE(1);
  #pragma unroll 2
  for (int k = 0; k < 8; ++k) {
    if (k < 7) WAIT_BARRIER(8); else WAIT_BARRIER(0);
    int b = k & 1;
    mfma_128x128(As[b], Bs[b], acc, wm, wn, l16, quad);
    RAW_BARRIER();
    if (k < 6) { if (b) FFN1_ISSUE(1); else FFN1_ISSUE(0); }
  }

  #pragma unroll
  for (int ni = 0; ni < 4; ++ni) {
    int col = n0 + wn * 64 + ni * 16 + l16;
    float bv = b1[e * NH + col];
    #pragma unroll
    for (int mi = 0; mi < 4; ++mi) {
      int rbase = wm * 64 + mi * 16 + quad * 4;
      #pragma unroll
      for (int r = 0; r < 4; ++r) {
        int grow = row0 + rbase + r;
        if (grow < row_end) {
          float v = acc[mi][ni][r] + bv;
          hbuf[(size_t)grow * NH + col] = f2bf(gelu_fast(v));
        }
      }
    }
  }
}

// ---------------- layer 2: out[token] = (h @ w2t[e]^T + b2[e]) * w_token ----------------
__global__ __launch_bounds__(256) void k_ffn2(
    const uint16_t* __restrict__ hbuf, const uint16_t* __restrict__ w2t,
    const float* __restrict__ b2,
    const int* __restrict__ offsets, const int* __restrict__ counts,
    const int* __restrict__ tile_e, const int* __restrict__ tile_r0,
    const int* __restrict__ perm, const float* __restrict__ wtok,
    float* __restrict__ out)
{
  int e = tile_e[blockIdx.x];
  if (e < 0) return;
  int row0 = tile_r0[blockIdx.x];
  int row_end = offsets[e] + counts[e];
  int n0 = blockIdx.y * 64;
  const uint16_t* Bt = w2t + (size_t)e * NH * DM;

  __shared__ uint16_t As[2][128 * 64];
  __shared__ uint16_t Bs[2][64 * 64];

  int tid = threadIdx.x;
  int lane = tid & 63, wid = tid >> 6;
  int wm = wid >> 1, wn = wid & 1;
  int l16 = lane & 15, quad = lane >> 4;

  int lrow = lane >> 3;
  int lsw  = (lane & 7) ^ lrow;
  const uint16_t *ga[4], *gb[2];
  int loa[4], lob[2];
  #pragma unroll
  for (int j = 0; j < 4; ++j) {
    int r = wid * 32 + j * 8;
    ga[j] = hbuf + (size_t)(row0 + r + lrow) * NH + lsw * 8;
    loa[j] = r * 64;
  }
  #pragma unroll
  for (int j = 0; j < 2; ++j) {
    int r = wid * 16 + j * 8;
    gb[j] = Bt + (size_t)(n0 + r + lrow) * NH + lsw * 8;
    lob[j] = r * 64;
  }

  #define FFN2_ISSUE(B) do { \
    _Pragma("unroll") for (int j = 0; j < 4; ++j) { gload_lds16(ga[j], As[B] + loa[j]); ga[j] += 64; } \
    _Pragma("unroll") for (int j = 0; j < 2; ++j) { gload_lds16(gb[j], Bs[B] + lob[j]); gb[j] += 64; } \
  } while (0)

  f32x4 acc[4][2] = {};

  FFN2_ISSUE(0);
  FFN2_ISSUE(1);
  #pragma unroll 2
  for (int k = 0; k < 32; ++k) {
    if (k < 31) WAIT_BARRIER(6); else WAIT_BARRIER(0);
    int b = k & 1;
    const uint16_t* Ab = As[b];
    const uint16_t* Bb = Bs[b];
    #pragma unroll
    for (int ks = 0; ks < 2; ++ks) {
      bf16x8 a[4], bb[2];
      #pragma unroll
      for (int mi = 0; mi < 4; ++mi) {
        int row = wm * 64 + mi * 16 + l16;
        a[mi] = *(const bf16x8*)(Ab + row * 64 + (((ks * 4 + quad) ^ (l16 & 7)) * 8));
      }
      #pragma unroll
      for (int ni = 0; ni < 2; ++ni) {
        int row = wn * 32 + ni * 16 + l16;
        bb[ni] = *(const bf16x8*)(Bb + row * 64 + (((ks * 4 + quad) ^ (l16 & 7)) * 8));
      }
      #pragma unroll
      for (int mi = 0; mi < 4; ++mi)
        #pragma unroll
        for (int ni = 0; ni < 2; ++ni)
          acc[mi][ni] = __builtin_amdgcn_mfma_f32_16x16x32_bf16(a[mi], bb[ni], acc[mi][ni], 0, 0, 0);
    }
    RAW_BARRIER();
    if (k < 30) { if (b) FFN2_ISSUE(1); else FFN2_ISSUE(0); }
  }

  #pragma unroll
  for (int ni = 0; ni < 2; ++ni) {
    int col = n0 + wn * 32 + ni * 16 + l16;
    float bv = b2[e * DM + col];
    #pragma unroll
    for (int mi = 0; mi < 4; ++mi) {
      int rbase = wm * 64 + mi * 16 + quad * 4;
      #pragma unroll
      for (int r = 0; r < 4; ++r) {
        int grow = row0 + rbase + r;
        if (grow < row_end) {
          int tk = perm[grow];
          float wt = wtok[tk];
          out[(size_t)tk * DM + col] = (acc[mi][ni][r] + bv) * wt;
        }
      }
    }
  }
}

extern "C" void kernel_launch(void* const* d_in, const int* in_sizes, int n_in,
                              void* d_out, int out_size, void* d_ws, size_t ws_size,
                              hipStream_t stream)
{
  const float* x  = (const float*)d_in[0];
  const float* u  = (const float*)d_in[1];
  const float* rw = (const float*)d_in[2];
  const float* rb = (const float*)d_in[3];
  const float* w1 = (const float*)d_in[4];
  const float* b1 = (const float*)d_in[5];
  const float* w2 = (const float*)d_in[6];
  const float* b2 = (const float*)d_in[7];
  float* out = (float*)d_out;

  char* ws = (char*)d_ws;
  int*      counts     = (int*)(ws + WS_COUNTS);
  int*      offsets    = (int*)(ws + WS_OFFSETS);
  float*    imp        = (float*)(ws + WS_IMP);
  int*      tile_e     = (int*)(ws + WS_TILE_E);
  int*      tile_r0    = (int*)(ws + WS_TILE_R0);
  int*      expert_of  = (int*)(ws + WS_EXP);
  float*    wtok       = (float*)(ws + WS_WTOK);
  int*      perm       = (int*)(ws + WS_PERM);
  float*    probs      = (float*)(ws + WS_PROBS);
  int*      rank_local = (int*)(ws + WS_RANK);
  int*      block_hist = (int*)(ws + WS_BHIST);
  int*      block_base = (int*)(ws + WS_BBASE);
  uint16_t* Xg         = (uint16_t*)(ws + WS_XG);
  uint16_t* hbuf       = (uint16_t*)(ws + WS_H);
  uint16_t* w1t        = (uint16_t*)(ws + WS_W1T);
  uint16_t* w2t        = (uint16_t*)(ws + WS_W2T);

  hipMemsetAsync(d_ws, 0, 128, stream);   // zeroes imp (counts/offsets rewritten anyway)
  k_transpose_bf16<<<dim3(NH / 64, DM / 64, NE), 256, 0, stream>>>(w1, w1t, DM, NH);
  k_transpose_bf16<<<dim3(DM / 64, NH / 64, NE), 256, 0, stream>>>(w2, w2t, NH, DM);
  k_router<<<NUM_TOK / 4, 256, 0, stream>>>(x, u, rw, rb, expert_of, wtok, probs);
  k_postroute<<<NBLK, 256, 0, stream>>>(expert_of, probs, rank_local, block_hist, imp);
  k_offsets<<<1, 256, 0, stream>>>(block_hist, imp, counts, offsets, block_base,
                                   out + (size_t)NUM_TOK * DM, tile_e, tile_r0);
  k_scatter2<<<NBLK, 256, 0, stream>>>(expert_of, rank_local, block_base, perm);
  k_gather<<<NUM_TOK, 64, 0, stream>>>(x, perm, Xg);
  k_ffn1<<<dim3(MAX_TILES, 16), 256, 0, stream>>>(Xg, w1t, b1, offsets, counts, tile_e, tile_r0, hbuf);
  k_ffn2<<<dim3(MAX_TILES, 8), 256, 0, stream>>>(hbuf, w2t, b2, offsets, counts, tile_e, tile_r0, perm, wtok, out);
}